// Round 1
// baseline (817.690 us; speedup 1.0000x reference)
//
#include <hip/hip_runtime.h>
#include <hip/hip_bf16.h>
#include <math.h>

#define VTAG 50257
#define EDIM 128
#define NREP 10
#define BFUNC 2048
#define NSTRIP 786          // ceil(50257/64)
#define NPAD (NSTRIP * 64)  // 50304

typedef __bf16 bf16x8 __attribute__((ext_vector_type(8)));
typedef float f32x4 __attribute__((ext_vector_type(4)));

__device__ __forceinline__ unsigned short f2bf(float x) {
    unsigned u = __float_as_uint(x);
    unsigned r = (u + 0x7fffu + ((u >> 16) & 1u)) >> 16;
    return (unsigned short)r;
}

// ---------------------------------------------------------------------------
// K1: per-function context encode + attention pool -> v (bf16) [B, E]
// block = 128 threads (thread = output channel e), grid = B
// ---------------------------------------------------------------------------
__global__ __launch_bounds__(128) void k1_attn(
    const int* __restrict__ v1i, const int* __restrict__ pti,
    const int* __restrict__ v2i,
    const float* __restrict__ vemb, const float* __restrict__ pemb,
    const float* __restrict__ Wfc, const float* __restrict__ bfc,
    const float* __restrict__ watt, const float* __restrict__ batt,
    unsigned short* __restrict__ vbf)
{
    const int b = blockIdx.x;
    const int e = threadIdx.x;              // 0..127
    __shared__ float ctx[NREP][3 * EDIM];   // 15360 B
    __shared__ float red[2][NREP];

    // cooperative gather of [10 x 384] context matrix (coalesced 128-chunks)
    #pragma unroll
    for (int j = 0; j < 30; ++j) {
        int i = j * 128 + e;
        int n = i / 384;                    // constant per j (384 = 3*128)
        int c = i - n * 384;
        float val;
        if (c < 128)      val = vemb[(size_t)v1i[b * NREP + n] * EDIM + c];
        else if (c < 256) val = pemb[(size_t)pti[b * NREP + n] * EDIM + (c - 128)];
        else              val = vemb[(size_t)v2i[b * NREP + n] * EDIM + (c - 256)];
        ctx[n][c] = val;
    }
    __syncthreads();

    // c_tilde[n][e] = tanh(b_fc[e] + sum_k ctx[n][k] * Wfc[k][e])
    float acc[NREP];
    #pragma unroll
    for (int n = 0; n < NREP; ++n) acc[n] = 0.f;

    for (int k = 0; k < 384; k += 4) {
        float w0 = Wfc[(k + 0) * EDIM + e];
        float w1 = Wfc[(k + 1) * EDIM + e];
        float w2 = Wfc[(k + 2) * EDIM + e];
        float w3 = Wfc[(k + 3) * EDIM + e];
        #pragma unroll
        for (int n = 0; n < NREP; ++n) {
            float4 c4 = *(const float4*)&ctx[n][k];
            acc[n] = fmaf(c4.x, w0, acc[n]);
            acc[n] = fmaf(c4.y, w1, acc[n]);
            acc[n] = fmaf(c4.z, w2, acc[n]);
            acc[n] = fmaf(c4.w, w3, acc[n]);
        }
    }

    const float bias = bfc[e];
    const float we = watt[e];
    float ct[NREP];
    #pragma unroll
    for (int n = 0; n < NREP; ++n) ct[n] = tanhf(acc[n] + bias);

    // attention logits: a[n] = sum_e ct[n][e] * w_att[e]  (reduce over 128 thr)
    const int wv = e >> 6, ln = e & 63;
    #pragma unroll
    for (int n = 0; n < NREP; ++n) {
        float p = ct[n] * we;
        p += __shfl_xor(p, 32);
        p += __shfl_xor(p, 16);
        p += __shfl_xor(p, 8);
        p += __shfl_xor(p, 4);
        p += __shfl_xor(p, 2);
        p += __shfl_xor(p, 1);
        if (ln == 0) red[wv][n] = p;
    }
    __syncthreads();

    const float batt0 = batt[0];
    float al[NREP];
    float m = -1e30f;
    #pragma unroll
    for (int n = 0; n < NREP; ++n) {
        al[n] = red[0][n] + red[1][n] + batt0;
        m = fmaxf(m, al[n]);
    }
    float s = 0.f;
    #pragma unroll
    for (int n = 0; n < NREP; ++n) { al[n] = __expf(al[n] - m); s += al[n]; }
    const float inv = 1.f / s;

    float v = 0.f;
    #pragma unroll
    for (int n = 0; n < NREP; ++n) v = fmaf(al[n] * inv, ct[n], v);

    vbf[b * EDIM + e] = f2bf(v);
}

// ---------------------------------------------------------------------------
// Kconv: tag_emb fp32 [VT,128] -> bf16 [NPAD,128], zero-padded rows
// ---------------------------------------------------------------------------
__global__ __launch_bounds__(256) void k_conv_tag(
    const float* __restrict__ tag, unsigned short* __restrict__ tbf)
{
    size_t i = ((size_t)blockIdx.x * 256 + threadIdx.x) * 4;
    if (i >= (size_t)NPAD * EDIM) return;
    float4 x = make_float4(0.f, 0.f, 0.f, 0.f);
    if (i < (size_t)VTAG * EDIM) x = *(const float4*)(tag + i);
    ushort4 o;
    o.x = f2bf(x.x); o.y = f2bf(x.y); o.z = f2bf(x.z); o.w = f2bf(x.w);
    *(ushort4*)(tbf + i) = o;
}

// ---------------------------------------------------------------------------
// K2: logits = v @ tag^T via bf16 MFMA 16x16x32.
// block = 256 thr = 4 waves; wave covers 32 rows (2 m-tiles) x 64 cols.
// grid = (B/128, NSTRIP). Writes raw logits to out + per-strip max/sumexp.
// ---------------------------------------------------------------------------
__global__ __launch_bounds__(256) void k2_logits(
    const unsigned short* __restrict__ vbf, const unsigned short* __restrict__ tbf,
    float* __restrict__ out, float* __restrict__ pmax, float* __restrict__ psum)
{
    const int wave = threadIdx.x >> 6;
    const int lane = threadIdx.x & 63;
    const int quad = lane >> 4;
    const int l16  = lane & 15;
    const int strip = blockIdx.y;
    const int n0 = strip * 64;
    const int rowbase = blockIdx.x * 128 + wave * 32;

    const bf16x8* tb8 = (const bf16x8*)tbf;  // unit = 16 B = 8 bf16
    const bf16x8* vb8 = (const bf16x8*)vbf;

    // B frags: lane holds tag[col = n0+nt*16+l16][k = ks*32 + quad*8 + j]
    bf16x8 bfrag[4][4];
    #pragma unroll
    for (int nt = 0; nt < 4; ++nt) {
        int col = n0 + nt * 16 + l16;
        const bf16x8* p = tb8 + (size_t)col * 16 + quad;
        #pragma unroll
        for (int ks = 0; ks < 4; ++ks) bfrag[nt][ks] = p[ks * 4];
    }
    // A frags: lane holds v[row = rowbase+mt*16+l16][k = ks*32 + quad*8 + j]
    bf16x8 afrag[2][4];
    #pragma unroll
    for (int mt = 0; mt < 2; ++mt) {
        int row = rowbase + mt * 16 + l16;
        const bf16x8* p = vb8 + (size_t)row * 16 + quad;
        #pragma unroll
        for (int ks = 0; ks < 4; ++ks) afrag[mt][ks] = p[ks * 4];
    }

    f32x4 acc[2][4];
    #pragma unroll
    for (int mt = 0; mt < 2; ++mt)
        #pragma unroll
        for (int nt = 0; nt < 4; ++nt) acc[mt][nt] = (f32x4){0.f, 0.f, 0.f, 0.f};

    #pragma unroll
    for (int ks = 0; ks < 4; ++ks)
        #pragma unroll
        for (int mt = 0; mt < 2; ++mt)
            #pragma unroll
            for (int nt = 0; nt < 4; ++nt)
                acc[mt][nt] = __builtin_amdgcn_mfma_f32_16x16x32_bf16(
                    afrag[mt][ks], bfrag[nt][ks], acc[mt][nt], 0, 0, 0);

    // epilogue: D[row = quad*4 + r][col = l16] per 16x16 tile (HW-verified map)
    #pragma unroll
    for (int mt = 0; mt < 2; ++mt) {
        #pragma unroll
        for (int r = 0; r < 4; ++r) {
            const int row = rowbase + mt * 16 + quad * 4 + r;
            float lm = -1e30f;
            #pragma unroll
            for (int nt = 0; nt < 4; ++nt) {
                int col = n0 + nt * 16 + l16;
                float x = acc[mt][nt][r];
                if (col < VTAG) lm = fmaxf(lm, x);
            }
            lm = fmaxf(lm, __shfl_xor(lm, 1));
            lm = fmaxf(lm, __shfl_xor(lm, 2));
            lm = fmaxf(lm, __shfl_xor(lm, 4));
            lm = fmaxf(lm, __shfl_xor(lm, 8));
            float ls = 0.f;
            #pragma unroll
            for (int nt = 0; nt < 4; ++nt) {
                int col = n0 + nt * 16 + l16;
                float x = acc[mt][nt][r];
                if (col < VTAG) {
                    ls += __expf(x - lm);
                    out[(size_t)row * VTAG + col] = x;
                }
            }
            ls += __shfl_xor(ls, 1);
            ls += __shfl_xor(ls, 2);
            ls += __shfl_xor(ls, 4);
            ls += __shfl_xor(ls, 8);
            if (l16 == 0) {
                pmax[(size_t)row * NSTRIP + strip] = lm;
                psum[(size_t)row * NSTRIP + strip] = ls;
            }
        }
    }
}

// ---------------------------------------------------------------------------
// K3: reduce NSTRIP partials per row -> row max M and 1/S
// one wave per row; grid = B/4, block = 256
// ---------------------------------------------------------------------------
__global__ __launch_bounds__(256) void k3_reduce(
    const float* __restrict__ pmax, const float* __restrict__ psum,
    float* __restrict__ rowM, float* __restrict__ rowR)
{
    const int row = blockIdx.x * 4 + (threadIdx.x >> 6);
    const int ln = threadIdx.x & 63;
    const float* pm = pmax + (size_t)row * NSTRIP;
    const float* ps = psum + (size_t)row * NSTRIP;

    float m = -1e30f;
    for (int i = ln; i < NSTRIP; i += 64) m = fmaxf(m, pm[i]);
    m = fmaxf(m, __shfl_xor(m, 32));
    m = fmaxf(m, __shfl_xor(m, 16));
    m = fmaxf(m, __shfl_xor(m, 8));
    m = fmaxf(m, __shfl_xor(m, 4));
    m = fmaxf(m, __shfl_xor(m, 2));
    m = fmaxf(m, __shfl_xor(m, 1));

    float s = 0.f;
    for (int i = ln; i < NSTRIP; i += 64) s += ps[i] * __expf(pm[i] - m);
    s += __shfl_xor(s, 32);
    s += __shfl_xor(s, 16);
    s += __shfl_xor(s, 8);
    s += __shfl_xor(s, 4);
    s += __shfl_xor(s, 2);
    s += __shfl_xor(s, 1);

    if (ln == 0) { rowM[row] = m; rowR[row] = 1.f / s; }
}

// ---------------------------------------------------------------------------
// K4: in-place normalize: q = exp(l - M[row]) * R[row]
// flat float4 indexing (16B-aligned); row via constant division
// ---------------------------------------------------------------------------
__global__ __launch_bounds__(256) void k4_norm(
    float* __restrict__ out, const float* __restrict__ rowM,
    const float* __restrict__ rowR)
{
    unsigned i0 = (blockIdx.x * 256u + threadIdx.x) * 4u;
    const unsigned total = (unsigned)BFUNC * VTAG;
    if (i0 >= total) return;
    unsigned row = i0 / VTAG;                 // compile-time magic div
    unsigned c = i0 - row * VTAG;
    if (c + 4 <= VTAG) {
        float M = rowM[row], R = rowR[row];
        float4 x = *(float4*)(out + i0);
        x.x = __expf(x.x - M) * R;
        x.y = __expf(x.y - M) * R;
        x.z = __expf(x.z - M) * R;
        x.w = __expf(x.w - M) * R;
        *(float4*)(out + i0) = x;
    } else {
        #pragma unroll
        for (int j = 0; j < 4; ++j) {
            unsigned i = i0 + j;
            unsigned r2 = i / VTAG;
            out[i] = __expf(out[i] - rowM[r2]) * rowR[r2];
        }
    }
}

// ---------------------------------------------------------------------------
extern "C" void kernel_launch(void* const* d_in, const int* in_sizes, int n_in,
                              void* d_out, int out_size, void* d_ws, size_t ws_size,
                              hipStream_t stream)
{
    const int*   v1i  = (const int*)d_in[0];
    const int*   pti  = (const int*)d_in[1];
    const int*   v2i  = (const int*)d_in[2];
    const float* vemb = (const float*)d_in[3];
    const float* pemb = (const float*)d_in[4];
    const float* temb = (const float*)d_in[5];
    const float* Wfc  = (const float*)d_in[6];
    const float* bfc  = (const float*)d_in[7];
    const float* watt = (const float*)d_in[8];
    const float* batt = (const float*)d_in[9];
    float* out = (float*)d_out;

    char* ws = (char*)d_ws;
    const size_t vbf_off  = 0;                                   // 2048*128*2   = 524288
    const size_t tbf_off  = vbf_off + 524288;                    // 50304*128*2  = 12877824
    const size_t pmax_off = tbf_off + 12877824;                  // 2048*786*4   = 6438912
    const size_t psum_off = pmax_off + 6438912;
    const size_t rowm_off = psum_off + 6438912;
    const size_t rowr_off = rowm_off + 8192;

    unsigned short* vbf = (unsigned short*)(ws + vbf_off);
    unsigned short* tbf = (unsigned short*)(ws + tbf_off);
    float* pmax = (float*)(ws + pmax_off);
    float* psum = (float*)(ws + psum_off);
    float* rowM = (float*)(ws + rowm_off);
    float* rowR = (float*)(ws + rowr_off);

    hipLaunchKernelGGL(k1_attn, dim3(BFUNC), dim3(128), 0, stream,
                       v1i, pti, v2i, vemb, pemb, Wfc, bfc, watt, batt, vbf);
    hipLaunchKernelGGL(k_conv_tag, dim3((NPAD * EDIM / 4 + 255) / 256), dim3(256),
                       0, stream, temb, tbf);
    hipLaunchKernelGGL(k2_logits, dim3(BFUNC / 128, NSTRIP), dim3(256), 0, stream,
                       vbf, tbf, out, pmax, psum);
    hipLaunchKernelGGL(k3_reduce, dim3(BFUNC / 4), dim3(256), 0, stream,
                       pmax, psum, rowM, rowR);
    hipLaunchKernelGGL(k4_norm, dim3(((unsigned)BFUNC * VTAG / 4 + 255) / 256),
                       dim3(256), 0, stream, out, rowM, rowR);
}